// Round 13
// baseline (51.844 us; speedup 1.0000x reference)
//
#include <hip/hip_runtime.h>
#include <hip/hip_fp16.h>

#define SDIM 1024

typedef _Float16 f16;
typedef _Float16 f16x8 __attribute__((ext_vector_type(8)));
typedef __attribute__((ext_vector_type(4))) float f32x4;

union FragH { unsigned int u[4]; f16x8 f; uint4 q; };

// compile-time packed f16x2 constants
constexpr unsigned short f16bits(float x) {
    return __builtin_bit_cast(unsigned short, (_Float16)x);
}
constexpr unsigned int pk2(float x) {
    return (unsigned int)f16bits(x) * 0x10001u;
}

// trans-free poly gelu, EXACT 15-instruction asm (all VOP3P, <=1 SGPR const each,
// no literals/inline-consts in VOP3P). g = t*(0.5 + tc*W'(x)), tc=clamp(t,+-3),
// x = tc^2*(2/9)-1, W' = poly5(x) with coefficients pre-halved.
__device__ __forceinline__ unsigned int addgelu_pair(
    unsigned int au, unsigned int bu,
    unsigned int sLo, unsigned int sHi, unsigned int sXA, unsigned int sXB,
    unsigned int sC5, unsigned int sC4, unsigned int sC3, unsigned int sC2,
    unsigned int sC1, unsigned int sC0, unsigned int sHalf)
{
    unsigned int g, t, tc, x, w;
    asm("v_pk_add_f16 %1, %5, %6\n\t"          // t  = a + b
        "v_pk_max_f16 %2, %1, %7\n\t"          // tc = max(t, -3)
        "v_pk_min_f16 %2, %2, %8\n\t"          // tc = min(tc, 3)
        "v_pk_mul_f16 %3, %2, %2\n\t"          // x  = tc*tc
        "v_pk_mul_f16 %3, %3, %9\n\t"          // x *= 2/9
        "v_pk_add_f16 %3, %3, %10\n\t"         // x += -1
        "v_pk_mul_f16 %4, %3, %11\n\t"         // w  = x*C5'
        "v_pk_add_f16 %4, %4, %12\n\t"         // w += C4'
        "v_pk_fma_f16 %4, %4, %3, %13\n\t"     // w  = w*x + C3'
        "v_pk_fma_f16 %4, %4, %3, %14\n\t"     //           + C2'
        "v_pk_fma_f16 %4, %4, %3, %15\n\t"     //           + C1'
        "v_pk_fma_f16 %4, %4, %3, %16\n\t"     //           + C0'
        "v_pk_mul_f16 %4, %4, %2\n\t"          // w  = tc*W'
        "v_pk_add_f16 %4, %4, %17\n\t"         // w  = 0.5 + tc*W'
        "v_pk_mul_f16 %0, %1, %4"              // g  = t * w
        : "=v"(g), "=&v"(t), "=&v"(tc), "=&v"(x), "=&v"(w)
        : "v"(au), "v"(bu),
          "s"(sLo), "s"(sHi), "s"(sXA), "s"(sXB),
          "s"(sC5), "s"(sC4), "s"(sC3), "s"(sC2), "s"(sC1), "s"(sC0), "s"(sHalf));
    return g;
}

#define GELU_CONSTS  kLo, kHi, kXA, kXB, kC5, kC4, kC3, kC2, kC1, kC0, kHalf

// ---------------- Kernel 1: u,v (f16) + W2h = W2^T in f16 [16h][64k] ----------------
__global__ __launch_bounds__(256) void compute_uv(
    const float* __restrict__ x, const float* __restrict__ Wc,
    const float* __restrict__ bc, const float* __restrict__ W1,
    const float* __restrict__ b1, const float* __restrict__ W2,
    f16* __restrict__ u, f16* __restrict__ v, f16* __restrict__ W2h)
{
    __shared__ float xrow[4 * 1024];
    __shared__ float part[4 * 8 * 32];
    __shared__ float xc[4 * 32];
    const int tid = threadIdx.x;
    const size_t bs0 = (size_t)blockIdx.x * 4;

    if (blockIdx.x == 0) {   // one-time W2 transpose+convert (1024 elems)
        #pragma unroll
        for (int e = 0; e < 4; ++e) {
            const int flat = tid * 4 + e;          // flat = h*64 + k
            const int h = flat >> 6, k = flat & 63;
            W2h[flat] = (f16)W2[k * 16 + h];
        }
    }

    const float4* xin = (const float4*)(x + bs0 * 1024);
    #pragma unroll
    for (int it = 0; it < 4; ++it)
        ((float4*)xrow)[it * 256 + tid] = xin[it * 256 + tid];
    __syncthreads();
    {
        const int c = tid & 31, p = tid >> 5;
        float acc[4] = {0.f, 0.f, 0.f, 0.f};
        #pragma unroll 4
        for (int dd = 0; dd < 128; ++dd) {
            const int d = p * 128 + dd;
            const float wv = Wc[d * 32 + c];
            #pragma unroll
            for (int r = 0; r < 4; ++r)
                acc[r] = __builtin_fmaf(xrow[r * 1024 + d], wv, acc[r]);
        }
        #pragma unroll
        for (int r = 0; r < 4; ++r)
            part[r * 256 + p * 32 + c] = acc[r];
    }
    __syncthreads();
    if (tid < 128) {
        const int r = tid >> 5, c = tid & 31;
        float s = bc[c];
        #pragma unroll
        for (int p = 0; p < 8; ++p) s += part[r * 256 + p * 32 + c];
        xc[r * 32 + c] = s;
    }
    __syncthreads();
    {
        const int h = tid & 63;
        const int rr = tid >> 6;
        float ua = b1[h], va = 0.0f;
        #pragma unroll
        for (int cc = 0; cc < 32; ++cc) {
            const float xv = xc[rr * 32 + cc];
            ua = __builtin_fmaf(xv, W1[cc * 64 + h], ua);
            va = __builtin_fmaf(xv, W1[(32 + cc) * 64 + h], va);
        }
        u[(bs0 + rr) * 64 + h] = (f16)ua;
        v[(bs0 + rr) * 64 + h] = (f16)va;
    }
}

// ---------------- Kernel 2: out[b,h,i,j] = sum_k gelu(u[i,k]+v[j,k])*W2[k,h] + b2[h] --
// R12 structure: 32i x 32j tile, 4 waves (wave -> i-half x j-half), grid (32,32,2)
// = 2048 blocks. Gelu = 15-inst asm with SGPR constants (no VOP3P literal remat).
__global__ __launch_bounds__(256, 6) void prg_main(
    const f16* __restrict__ u, const f16* __restrict__ v,
    const f16* __restrict__ W2h, const float* __restrict__ b2,
    float* __restrict__ out)
{
    const int tid  = threadIdx.x;
    const int lane = tid & 63;
    const int w    = tid >> 6;
    const int jb   = blockIdx.x * 32;
    const int ib   = blockIdx.y * 32;
    const int b    = blockIdx.z;

    // gelu constants (compile-time packed f16x2; "s" constraints pin them in SGPRs)
    const unsigned int kLo   = pk2(-3.0f);
    const unsigned int kHi   = pk2( 3.0f);
    const unsigned int kXA   = pk2( 2.0f / 9.0f);
    const unsigned int kXB   = pk2(-1.0f);
    const unsigned int kC5   = pk2(-0.003456f);   // coefficients pre-halved
    const unsigned int kC4   = pk2( 0.009668f);
    const unsigned int kC3   = pk2(-0.020158f);
    const unsigned int kC2   = pk2( 0.045110f);
    const unsigned int kC1   = pk2(-0.092726f);
    const unsigned int kC0   = pk2( 0.2278245f);
    const unsigned int kHalf = pk2( 0.5f);

    __shared__ f16 u_lds[32][64];   // 4 KB

    {
        const int row = tid >> 3;
        const int col = (tid & 7) * 8;
        *(uint4*)&u_lds[row][col] =
            *(const uint4*)(u + ((size_t)(b * SDIM + ib + row) * 64 + col));
    }

    const int lg = lane >> 4;   // k-group 0..3
    const int lr = lane & 15;   // A row (j) / D col (h)
    const int k0 = lg * 8;
    const int jw = jb + (w & 1) * 16;   // wave's j-base
    const int iw = (w >> 1) * 16;       // wave's i-base within tile

    const f16* vp = v + ((size_t)(b * SDIM + jw + lr) * 64);
    const uint4 vlo = *(const uint4*)(vp + k0);
    const uint4 vhi = *(const uint4*)(vp + k0 + 32);

    FragH w2lo, w2hi;
    w2lo.q = *(const uint4*)(W2h + lr * 64 + k0);
    w2hi.q = *(const uint4*)(W2h + lr * 64 + k0 + 32);

    const float b2h = b2[lr];

    __syncthreads();

    float* ob = out + ((size_t)(b * 16 + lr) * SDIM + (ib + iw)) * SDIM + jw + lg * 4;

    #pragma unroll
    for (int g = 0; g < 4; ++g) {
        f32x4 acc[4];
        #pragma unroll
        for (int q = 0; q < 4; ++q) {
            const int il = iw + g * 4 + q;
            const uint4 alo = *(const uint4*)&u_lds[il][k0];
            const uint4 ahi = *(const uint4*)&u_lds[il][k0 + 32];
            FragH glo, ghi;
            glo.u[0] = addgelu_pair(alo.x, vlo.x, GELU_CONSTS);
            glo.u[1] = addgelu_pair(alo.y, vlo.y, GELU_CONSTS);
            glo.u[2] = addgelu_pair(alo.z, vlo.z, GELU_CONSTS);
            glo.u[3] = addgelu_pair(alo.w, vlo.w, GELU_CONSTS);
            ghi.u[0] = addgelu_pair(ahi.x, vhi.x, GELU_CONSTS);
            ghi.u[1] = addgelu_pair(ahi.y, vhi.y, GELU_CONSTS);
            ghi.u[2] = addgelu_pair(ahi.z, vhi.z, GELU_CONSTS);
            ghi.u[3] = addgelu_pair(ahi.w, vhi.w, GELU_CONSTS);
            f32x4 a = {b2h, b2h, b2h, b2h};
            a = __builtin_amdgcn_mfma_f32_16x16x32_f16(glo.f, w2lo.f, a, 0, 0, 0);
            a = __builtin_amdgcn_mfma_f32_16x16x32_f16(ghi.f, w2hi.f, a, 0, 0, 0);
            acc[q] = a;
        }
        #pragma unroll
        for (int q = 0; q < 4; ++q)
            *(float4*)(ob + (size_t)(g * 4 + q) * SDIM) = *(float4*)&acc[q];
    }
}

extern "C" void kernel_launch(void* const* d_in, const int* in_sizes, int n_in,
                              void* d_out, int out_size, void* d_ws, size_t ws_size,
                              hipStream_t stream) {
    const float* x  = (const float*)d_in[0];
    const float* Wc = (const float*)d_in[1];
    const float* bc = (const float*)d_in[2];
    const float* W1 = (const float*)d_in[3];
    const float* b1 = (const float*)d_in[4];
    const float* W2 = (const float*)d_in[5];
    const float* b2 = (const float*)d_in[6];
    float* out = (float*)d_out;

    f16* u   = (f16*)d_ws;                 // 256 KB
    f16* v   = u + 2 * SDIM * 64;          // 256 KB
    f16* W2h = v + 2 * SDIM * 64;          // 2 KB

    compute_uv<<<dim3(512), dim3(256), 0, stream>>>(x, Wc, bc, W1, b1, W2, u, v, W2h);
    prg_main<<<dim3(32, 32, 2), dim3(256), 0, stream>>>(u, v, W2h, b2, out);
}